// Round 4
// baseline (135.602 us; speedup 1.0000x reference)
//
#include <hip/hip_runtime.h>
#include <math.h>

#define BTOT 262144
#define R 3
#define F 4
#define H 16
#define A 18
#define SMALL_NUM_F 0.015f
#define MARGIN_TAU 1e-4f

// ---- ws header layout (float indices); flags byte-array follows at 768 B ----
#define WS_FLAG   0      // int: 1 = collapsed fast path valid (b1==0 && b2==0)
#define WS_KP     4      // +rf : collapsed slope, s_f > 0
#define WS_KM     20     // +rf : collapsed slope, s_f < 0
#define WS_G      40     // +rf : gs1 (0/1), uniform over batch
#define WS_COND   52     // +r  : cond flag (0/1)
#define WS_LEAVES 56     // + l*A + a : softmax(leaves_params) rows (4x18)
#define WS_B3     128    // +rf : copy of b3
#define WS_HDR_FLOATS 192
#define WS_HDR_BYTES  768

// ---------------------------------------------------------------------------
// Setup (1 block): all batch-uniform quantities, K± f64-accumulated.
// With b1=b2=0 each (r,f) MLP is piecewise-linear in s_f with one kink at 0:
// dot = s_f * K(sign(s_f)) + b3.
// ---------------------------------------------------------------------------
__global__ __launch_bounds__(256) void ftc_setup(
    const float* __restrict__ W1, const float* __restrict__ b1,
    const float* __restrict__ W2, const float* __restrict__ b2,
    const float* __restrict__ W3, const float* __restrict__ b3,
    const float* __restrict__ p_select, const float* __restrict__ gumbel,
    const float* __restrict__ leaves,
    float* __restrict__ ws)
{
    __shared__ int nz;
    __shared__ float sh_g[R * F];
    const int tid = threadIdx.x;
    if (tid == 0) nz = 0;
    __syncthreads();
    if (tid < R * F * H) {
        if (b1[tid] != 0.0f) atomicOr(&nz, 1);
        if (b2[tid] != 0.0f) atomicOr(&nz, 1);
    }

    if (tid < R * F) {   // g — verbatim round-1 float ops
        const int rf = tid;
        float l0 = p_select[rf * 2 + 0] + gumbel[rf * 2 + 0];
        float l1 = p_select[rf * 2 + 1] + gumbel[rf * 2 + 1];
        float mx = fmaxf(l0, l1);
        float e0 = expf(l0 - mx), e1 = expf(l1 - mx);
        float den = e0 + e1;
        float y0 = e0 / den, y1 = e1 / den;
        float ym = fmaxf(y0, y1);
        float g = (y1 == ym) ? 1.0f : 0.0f;
        sh_g[rf] = g;
        ws[WS_G + rf] = g;
        ws[WS_B3 + rf] = b3[rf];
    }
    if (tid < 4) {       // leaves softmax — verbatim round-1 float ops
        float mx = leaves[tid * A];
        for (int a = 1; a < A; ++a) mx = fmaxf(mx, leaves[tid * A + a]);
        float e[A];
        float sum = 0.f;
        for (int a = 0; a < A; ++a) { e[a] = expf(leaves[tid * A + a] - mx); sum += e[a]; }
        for (int a = 0; a < A; ++a) ws[WS_LEAVES + tid * A + a] = e[a] / sum;
    }
    if (tid < R * F) {   // K± collapse, f64
        const int rf = tid;
        double Kp = 0.0, Km = 0.0;
        for (int o = 0; o < H; ++o) {
            double Pp = 0.0, Pm = 0.0;
            for (int h = 0; h < H; ++h) {
                const double w1 = (double)W1[rf * H + h];
                const double w2 = (double)W2[rf * H * H + h * H + o];
                Pp += w1 * ((w1 > 0.0) ? 1.0 : 0.01) * w2;
                Pm += w1 * ((w1 < 0.0) ? 1.0 : 0.01) * w2;
            }
            const double w3 = (double)W3[rf * H + o];
            Kp += Pp * ((Pp > 0.0) ? 1.0 : 0.01) * w3;
            Km += Pm * ((Pm < 0.0) ? 1.0 : 0.01) * w3;
        }
        ws[WS_KP + rf] = (float)Kp;
        ws[WS_KM + rf] = (float)Km;
    }
    __syncthreads();
    if (tid == 0) ((int*)ws)[WS_FLAG] = (nz == 0) ? 1 : 0;
    if (tid < R) {
        float ssum = sh_g[tid * F + 0] + sh_g[tid * F + 1] + sh_g[tid * F + 2] + sh_g[tid * F + 3];
        ws[WS_COND + tid] = (ssum > SMALL_NUM_F) ? 1.0f : 0.0f;
    }
}

// ---------------------------------------------------------------------------
// Exact f32 chain — verbatim round-1 (measured absmax 0).
// ---------------------------------------------------------------------------
__device__ __forceinline__ void compute_m_exact(
    const float sf[F],
    const float* __restrict__ W1, const float* __restrict__ b1,
    const float* __restrict__ W2, const float* __restrict__ b2,
    const float* __restrict__ W3, const float* __restrict__ b3,
    float m[R][F])
{
#pragma unroll
    for (int r = 0; r < R; ++r) {
#pragma unroll
        for (int f = 0; f < F; ++f) {
            const int rf = r * F + f;
            const float* w1  = W1 + rf * H;
            const float* bb1 = b1 + rf * H;
            const float* w2  = W2 + rf * H * H;
            const float* bb2 = b2 + rf * H;
            const float* w3  = W3 + rf * H;
            float h1[H];
#pragma unroll
            for (int h = 0; h < H; ++h) {
                float v = fmaf(sf[f], w1[h], bb1[h]);
                h1[h] = fmaxf(v, 0.01f * v);
            }
            float acc[H];
#pragma unroll
            for (int o = 0; o < H; ++o) acc[o] = bb2[o];
#pragma unroll
            for (int h = 0; h < H; ++h) {
                const float hv = h1[h];
#pragma unroll
                for (int o = 0; o < H; ++o)
                    acc[o] = fmaf(hv, w2[h * H + o], acc[o]);
            }
            float dot = b3[rf];
#pragma unroll
            for (int o = 0; o < H; ++o) {
                float v = fmaxf(acc[o], 0.01f * acc[o]);
                dot = fmaf(v, w3[o], dot);
            }
            float mm = 1.0f / (1.0f + expf(-dot));
            m[r][f] = fmaxf(mm, SMALL_NUM_F);
        }
    }
}

__device__ __forceinline__ void compute_strength_exact(
    const float m[R][F], const float g[R][F], const float cond[R], float st[R])
{
#pragma unroll
    for (int r = 0; r < R; ++r) {
        const bool c = cond[r] != 0.0f;
        float X[F];
        float ssum = 0.f;
#pragma unroll
        for (int f = 0; f < F; ++f) {
            float gv = g[r][f];
            float xw = expf(0.1f * (gv / m[r][f]));
            if (c) xw *= gv;
            X[f] = xw;
            ssum += xw;
        }
        float sv = 0.f;
#pragma unroll
        for (int f = 0; f < F; ++f)
            sv += m[r][f] * (X[f] / ssum) * g[r][f];
        st[r] = isnan(sv) ? 0.0f : sv;
    }
}

__device__ __forceinline__ int path_argmax(const float st[R]) {
    const float r0 = st[0], r1 = st[1], r2 = st[2];
    const float p0 = r0 * r1;
    const float p1 = r0 * (1.0f - r1);
    const float p2 = (1.0f - r0) * r2;
    const float p3 = (1.0f - r0) * (1.0f - r2);
    int idx = 0;
    float best = p0;
    if (p1 > best) { best = p1; idx = 1; }
    if (p2 > best) { best = p2; idx = 2; }
    if (p3 > best) { best = p3; idx = 3; }
    return idx;
}

// ---------------------------------------------------------------------------
// Main kernel: fast path only. USE_FLAGS=1 -> flag ambiguous elements for the
// cleanup pass; USE_FLAGS=0 -> inline divergent fallback (ws too small).
// ---------------------------------------------------------------------------
template<bool USE_FLAGS>
__global__ __launch_bounds__(256) void ftc_main(
    const float* __restrict__ s,
    const float* __restrict__ W1, const float* __restrict__ b1,
    const float* __restrict__ W2, const float* __restrict__ b2,
    const float* __restrict__ W3, const float* __restrict__ b3,
    const float* __restrict__ ws,
    unsigned char* __restrict__ flags,
    float* __restrict__ out)
{
    __shared__ float sh_hdr[WS_HDR_FLOATS];
    __shared__ unsigned char sh_idx[256];

    const int tid = threadIdx.x;
    if (tid < WS_HDR_FLOATS) sh_hdr[tid] = ws[tid];
    __syncthreads();

    const int flag = (int)__float_as_uint(sh_hdr[WS_FLAG]);

    const int b = blockIdx.x * 256 + tid;
    const float4 sv = *reinterpret_cast<const float4*>(s + (size_t)b * F);
    const float sf[F] = {sv.x, sv.y, sv.z, sv.w};

    float st[R];
    bool need_exact = true;

    if (flag) {
        // fast path: 1/m = min(1 + e^{-dot}, 1/0.015); ~3 transcendentals per rf
#pragma unroll
        for (int r = 0; r < R; ++r) {
            const bool c = sh_hdr[WS_COND + r] != 0.0f;
            float num = 0.f, den = 0.f;
#pragma unroll
            for (int f = 0; f < F; ++f) {
                const int rf = r * F + f;
                const float k = (sf[f] > 0.0f) ? sh_hdr[WS_KP + rf] : sh_hdr[WS_KM + rf];
                const float dot = fmaf(sf[f], k, sh_hdr[WS_B3 + rf]);
                const float inv_m = fminf(1.0f + __expf(-dot), 1.0f / SMALL_NUM_F);
                const float mm = __builtin_amdgcn_rcpf(inv_m);
                const float g = sh_hdr[WS_G + rf];
                float xw = __expf(0.1f * g * inv_m);
                if (c) xw *= g;
                num = fmaf(mm * xw, g, num);
                den += xw;
            }
            st[r] = num * __builtin_amdgcn_rcpf(den);
        }
        // top-2 margin of the 4 path probs; NaN-safe (NaN -> need_exact)
        const float r0 = st[0], r1 = st[1], r2 = st[2];
        const float p0 = r0 * r1;
        const float p1 = r0 * (1.0f - r1);
        const float p2 = (1.0f - r0) * r2;
        const float p3 = (1.0f - r0) * (1.0f - r2);
        const float a = fmaxf(p0, p1), bb = fminf(p0, p1);
        const float c2 = fmaxf(p2, p3), d = fminf(p2, p3);
        const float best = fmaxf(a, c2);
        const float second = fmaxf(fminf(a, c2), (a >= c2) ? bb : d);
        need_exact = !((best - second) > MARGIN_TAU);
    }

    if constexpr (USE_FLAGS) {
        if (flag) {
            flags[b] = need_exact ? 1 : 0;   // cleanup pass fixes flagged rows
        } else {
            // uniform all-exact fallback (b1/b2 nonzero) — no cleanup needed
            float g[R][F], cond[R], m[R][F];
#pragma unroll
            for (int r = 0; r < R; ++r) {
                cond[r] = sh_hdr[WS_COND + r];
#pragma unroll
                for (int f = 0; f < F; ++f) g[r][f] = sh_hdr[WS_G + r * F + f];
            }
            compute_m_exact(sf, W1, b1, W2, b2, W3, b3, m);
            compute_strength_exact(m, g, cond, st);
            flags[b] = 0;
        }
    } else {
        if (need_exact) {
            float g[R][F], cond[R], m[R][F];
#pragma unroll
            for (int r = 0; r < R; ++r) {
                cond[r] = sh_hdr[WS_COND + r];
#pragma unroll
                for (int f = 0; f < F; ++f) g[r][f] = sh_hdr[WS_G + r * F + f];
            }
            compute_m_exact(sf, W1, b1, W2, b2, W3, b3, m);
            compute_strength_exact(m, g, cond, st);
        }
    }

    sh_idx[tid] = (unsigned char)path_argmax(st);
    __syncthreads();

    float* outb = out + (size_t)blockIdx.x * (256 * A);
    for (int i = tid; i < 256 * A; i += 256) {
        int bl = i / A;
        int a  = i - bl * A;
        outb[i] = sh_hdr[WS_LEAVES + (int)sh_idx[bl] * A + a];
    }
}

// ---------------------------------------------------------------------------
// Cleanup: exact recompute for flagged elements only (~0.1%).
// ---------------------------------------------------------------------------
__global__ __launch_bounds__(256) void ftc_cleanup(
    const float* __restrict__ s,
    const float* __restrict__ W1, const float* __restrict__ b1,
    const float* __restrict__ W2, const float* __restrict__ b2,
    const float* __restrict__ W3, const float* __restrict__ b3,
    const float* __restrict__ ws,
    const unsigned char* __restrict__ flags,
    float* __restrict__ out)
{
    for (int e = blockIdx.x * 256 + threadIdx.x; e < BTOT; e += 256 * 256) {
        if (flags[e] == 0) continue;
        const float4 sv = *reinterpret_cast<const float4*>(s + (size_t)e * F);
        const float sf[F] = {sv.x, sv.y, sv.z, sv.w};
        float g[R][F], cond[R], m[R][F], st[R];
#pragma unroll
        for (int r = 0; r < R; ++r) {
            cond[r] = ws[WS_COND + r];
#pragma unroll
            for (int f = 0; f < F; ++f) g[r][f] = ws[WS_G + r * F + f];
        }
        compute_m_exact(sf, W1, b1, W2, b2, W3, b3, m);
        compute_strength_exact(m, g, cond, st);
        const int idx = path_argmax(st);
#pragma unroll
        for (int a = 0; a < A; ++a)
            out[(size_t)e * A + a] = ws[WS_LEAVES + idx * A + a];
    }
}

extern "C" void kernel_launch(void* const* d_in, const int* in_sizes, int n_in,
                              void* d_out, int out_size, void* d_ws, size_t ws_size,
                              hipStream_t stream) {
    const float* s  = (const float*)d_in[0];
    const float* W1 = (const float*)d_in[1];
    const float* b1 = (const float*)d_in[2];
    const float* W2 = (const float*)d_in[3];
    const float* b2 = (const float*)d_in[4];
    const float* W3 = (const float*)d_in[5];
    const float* b3 = (const float*)d_in[6];
    const float* ps = (const float*)d_in[7];
    const float* lv = (const float*)d_in[8];
    const float* gn = (const float*)d_in[9];
    float* ws  = (float*)d_ws;
    float* out = (float*)d_out;
    unsigned char* flags = (unsigned char*)d_ws + WS_HDR_BYTES;
    const bool use_flags = ws_size >= (size_t)(WS_HDR_BYTES + BTOT);

    hipLaunchKernelGGL(ftc_setup, dim3(1), dim3(256), 0, stream,
                       W1, b1, W2, b2, W3, b3, ps, gn, lv, ws);
    if (use_flags) {
        hipLaunchKernelGGL((ftc_main<true>), dim3(BTOT / 256), dim3(256), 0, stream,
                           s, W1, b1, W2, b2, W3, b3, ws, flags, out);
        hipLaunchKernelGGL(ftc_cleanup, dim3(256), dim3(256), 0, stream,
                           s, W1, b1, W2, b2, W3, b3, ws, flags, out);
    } else {
        hipLaunchKernelGGL((ftc_main<false>), dim3(BTOT / 256), dim3(256), 0, stream,
                           s, W1, b1, W2, b2, W3, b3, ws, (unsigned char*)nullptr, out);
    }
}

// Round 5
// 89.481 us; speedup vs baseline: 1.5154x; 1.5154x over previous
//
#include <hip/hip_runtime.h>
#include <math.h>

#define BTOT 262144
#define R 3
#define F 4
#define H 16
#define A 18
#define SMALL_NUM_F 0.015f
#define MARGIN_TAU 1e-4f

// ---- ws header layout (float indices); index list follows at 768 B ----
#define WS_FLAG   0      // int: 1 = collapsed fast path valid (b1==0 && b2==0)
#define WS_COUNT  1      // int: number of flagged (ambiguous) elements
#define WS_KP     4      // +rf : collapsed slope, s_f > 0
#define WS_KM     20     // +rf : collapsed slope, s_f < 0
#define WS_G      40     // +rf : gs1 (0/1), uniform over batch
#define WS_COND   52     // +r  : cond flag (0/1)
#define WS_LEAVES 56     // + l*A + a : softmax(leaves_params) rows (4x18)
#define WS_B3     128    // +rf : copy of b3
#define WS_HDR_FLOATS 192
#define WS_HDR_BYTES  768

// ---------------------------------------------------------------------------
// Setup (1 block): batch-uniform quantities; K± f64-accumulated.
// With b1=b2=0 each (r,f) MLP is piecewise-linear in s_f with one kink at 0:
// dot = s_f * K(sign(s_f)) + b3.
// ---------------------------------------------------------------------------
__global__ __launch_bounds__(256) void ftc_setup(
    const float* __restrict__ W1, const float* __restrict__ b1,
    const float* __restrict__ W2, const float* __restrict__ b2,
    const float* __restrict__ W3, const float* __restrict__ b3,
    const float* __restrict__ p_select, const float* __restrict__ gumbel,
    const float* __restrict__ leaves,
    float* __restrict__ ws)
{
    __shared__ int nz;
    __shared__ float sh_g[R * F];
    const int tid = threadIdx.x;
    if (tid == 0) nz = 0;
    __syncthreads();
    if (tid < R * F * H) {
        if (b1[tid] != 0.0f) atomicOr(&nz, 1);
        if (b2[tid] != 0.0f) atomicOr(&nz, 1);
    }

    if (tid < R * F) {   // g — verbatim round-1 float ops
        const int rf = tid;
        float l0 = p_select[rf * 2 + 0] + gumbel[rf * 2 + 0];
        float l1 = p_select[rf * 2 + 1] + gumbel[rf * 2 + 1];
        float mx = fmaxf(l0, l1);
        float e0 = expf(l0 - mx), e1 = expf(l1 - mx);
        float den = e0 + e1;
        float y0 = e0 / den, y1 = e1 / den;
        float ym = fmaxf(y0, y1);
        float g = (y1 == ym) ? 1.0f : 0.0f;
        sh_g[rf] = g;
        ws[WS_G + rf] = g;
        ws[WS_B3 + rf] = b3[rf];
    }
    if (tid < 4) {       // leaves softmax — verbatim round-1 float ops
        float mx = leaves[tid * A];
        for (int a = 1; a < A; ++a) mx = fmaxf(mx, leaves[tid * A + a]);
        float e[A];
        float sum = 0.f;
        for (int a = 0; a < A; ++a) { e[a] = expf(leaves[tid * A + a] - mx); sum += e[a]; }
        for (int a = 0; a < A; ++a) ws[WS_LEAVES + tid * A + a] = e[a] / sum;
    }
    if (tid < R * F) {   // K± collapse, f64
        const int rf = tid;
        double Kp = 0.0, Km = 0.0;
        for (int o = 0; o < H; ++o) {
            double Pp = 0.0, Pm = 0.0;
            for (int h = 0; h < H; ++h) {
                const double w1 = (double)W1[rf * H + h];
                const double w2 = (double)W2[rf * H * H + h * H + o];
                Pp += w1 * ((w1 > 0.0) ? 1.0 : 0.01) * w2;
                Pm += w1 * ((w1 < 0.0) ? 1.0 : 0.01) * w2;
            }
            const double w3 = (double)W3[rf * H + o];
            Kp += Pp * ((Pp > 0.0) ? 1.0 : 0.01) * w3;
            Km += Pm * ((Pm < 0.0) ? 1.0 : 0.01) * w3;
        }
        ws[WS_KP + rf] = (float)Kp;
        ws[WS_KM + rf] = (float)Km;
    }
    __syncthreads();
    if (tid == 0) {
        ((int*)ws)[WS_FLAG]  = (nz == 0) ? 1 : 0;
        ((int*)ws)[WS_COUNT] = 0;            // re-zeroed every launch (replay-safe)
    }
    if (tid < R) {
        float ssum = sh_g[tid * F + 0] + sh_g[tid * F + 1] + sh_g[tid * F + 2] + sh_g[tid * F + 3];
        ws[WS_COND + tid] = (ssum > SMALL_NUM_F) ? 1.0f : 0.0f;
    }
}

// ---------------------------------------------------------------------------
// Exact f32 chain — verbatim round-1 (measured absmax 0).
// ---------------------------------------------------------------------------
__device__ __forceinline__ void compute_m_exact(
    const float sf[F],
    const float* __restrict__ W1, const float* __restrict__ b1,
    const float* __restrict__ W2, const float* __restrict__ b2,
    const float* __restrict__ W3, const float* __restrict__ b3,
    float m[R][F])
{
#pragma unroll
    for (int r = 0; r < R; ++r) {
#pragma unroll
        for (int f = 0; f < F; ++f) {
            const int rf = r * F + f;
            const float* w1  = W1 + rf * H;
            const float* bb1 = b1 + rf * H;
            const float* w2  = W2 + rf * H * H;
            const float* bb2 = b2 + rf * H;
            const float* w3  = W3 + rf * H;
            float h1[H];
#pragma unroll
            for (int h = 0; h < H; ++h) {
                float v = fmaf(sf[f], w1[h], bb1[h]);
                h1[h] = fmaxf(v, 0.01f * v);
            }
            float acc[H];
#pragma unroll
            for (int o = 0; o < H; ++o) acc[o] = bb2[o];
#pragma unroll
            for (int h = 0; h < H; ++h) {
                const float hv = h1[h];
#pragma unroll
                for (int o = 0; o < H; ++o)
                    acc[o] = fmaf(hv, w2[h * H + o], acc[o]);
            }
            float dot = b3[rf];
#pragma unroll
            for (int o = 0; o < H; ++o) {
                float v = fmaxf(acc[o], 0.01f * acc[o]);
                dot = fmaf(v, w3[o], dot);
            }
            float mm = 1.0f / (1.0f + expf(-dot));
            m[r][f] = fmaxf(mm, SMALL_NUM_F);
        }
    }
}

__device__ __forceinline__ void compute_strength_exact(
    const float m[R][F], const float g[R][F], const float cond[R], float st[R])
{
#pragma unroll
    for (int r = 0; r < R; ++r) {
        const bool c = cond[r] != 0.0f;
        float X[F];
        float ssum = 0.f;
#pragma unroll
        for (int f = 0; f < F; ++f) {
            float gv = g[r][f];
            float xw = expf(0.1f * (gv / m[r][f]));
            if (c) xw *= gv;
            X[f] = xw;
            ssum += xw;
        }
        float sv = 0.f;
#pragma unroll
        for (int f = 0; f < F; ++f)
            sv += m[r][f] * (X[f] / ssum) * g[r][f];
        st[r] = isnan(sv) ? 0.0f : sv;
    }
}

__device__ __forceinline__ int path_argmax(const float st[R]) {
    const float r0 = st[0], r1 = st[1], r2 = st[2];
    const float p0 = r0 * r1;
    const float p1 = r0 * (1.0f - r1);
    const float p2 = (1.0f - r0) * r2;
    const float p3 = (1.0f - r0) * (1.0f - r2);
    int idx = 0;
    float best = p0;
    if (p1 > best) { best = p1; idx = 1; }
    if (p2 > best) { best = p2; idx = 2; }
    if (p3 > best) { best = p3; idx = 3; }
    return idx;
}

// ---------------------------------------------------------------------------
// Main: fast path; ambiguous elements are appended to a compact index list
// (USE_LIST=1) or recomputed inline (USE_LIST=0, ws too small).
// ---------------------------------------------------------------------------
template<bool USE_LIST>
__global__ __launch_bounds__(256) void ftc_main(
    const float* __restrict__ s,
    const float* __restrict__ W1, const float* __restrict__ b1,
    const float* __restrict__ W2, const float* __restrict__ b2,
    const float* __restrict__ W3, const float* __restrict__ b3,
    float* __restrict__ ws,
    unsigned int* __restrict__ list,
    float* __restrict__ out)
{
    __shared__ float sh_hdr[WS_HDR_FLOATS];
    __shared__ unsigned char sh_idx[256];

    const int tid = threadIdx.x;
    if (tid < WS_HDR_FLOATS) sh_hdr[tid] = ws[tid];
    __syncthreads();

    const int flag = (int)__float_as_uint(sh_hdr[WS_FLAG]);

    const int b = blockIdx.x * 256 + tid;
    const float4 sv = *reinterpret_cast<const float4*>(s + (size_t)b * F);
    const float sf[F] = {sv.x, sv.y, sv.z, sv.w};

    float st[R];
    bool need_exact = true;

    if (flag) {
        // fast path: 1/m = min(1 + e^{-dot}, 1/0.015)
#pragma unroll
        for (int r = 0; r < R; ++r) {
            const bool c = sh_hdr[WS_COND + r] != 0.0f;
            float num = 0.f, den = 0.f;
#pragma unroll
            for (int f = 0; f < F; ++f) {
                const int rf = r * F + f;
                const float k = (sf[f] > 0.0f) ? sh_hdr[WS_KP + rf] : sh_hdr[WS_KM + rf];
                const float dot = fmaf(sf[f], k, sh_hdr[WS_B3 + rf]);
                const float inv_m = fminf(1.0f + __expf(-dot), 1.0f / SMALL_NUM_F);
                const float mm = __builtin_amdgcn_rcpf(inv_m);
                const float g = sh_hdr[WS_G + rf];
                float xw = __expf(0.1f * g * inv_m);
                if (c) xw *= g;
                num = fmaf(mm * xw, g, num);
                den += xw;
            }
            st[r] = num * __builtin_amdgcn_rcpf(den);
        }
        // top-2 margin of the 4 path probs; NaN-safe (NaN -> ambiguous)
        const float r0 = st[0], r1 = st[1], r2 = st[2];
        const float p0 = r0 * r1;
        const float p1 = r0 * (1.0f - r1);
        const float p2 = (1.0f - r0) * r2;
        const float p3 = (1.0f - r0) * (1.0f - r2);
        const float a = fmaxf(p0, p1), bb = fminf(p0, p1);
        const float c2 = fmaxf(p2, p3), d = fminf(p2, p3);
        const float best = fmaxf(a, c2);
        const float second = fmaxf(fminf(a, c2), (a >= c2) ? bb : d);
        need_exact = !((best - second) > MARGIN_TAU);
    }

    if constexpr (USE_LIST) {
        if (flag) {
            if (need_exact) {   // ~0.5-1% of lanes: enqueue for dense cleanup
                unsigned int pos = atomicAdd((unsigned int*)ws + WS_COUNT, 1u);
                list[pos] = (unsigned int)b;
            }
        } else {
            float g[R][F], cond[R], m[R][F];
#pragma unroll
            for (int r = 0; r < R; ++r) {
                cond[r] = sh_hdr[WS_COND + r];
#pragma unroll
                for (int f = 0; f < F; ++f) g[r][f] = sh_hdr[WS_G + r * F + f];
            }
            compute_m_exact(sf, W1, b1, W2, b2, W3, b3, m);
            compute_strength_exact(m, g, cond, st);
        }
    } else {
        if (need_exact) {
            float g[R][F], cond[R], m[R][F];
#pragma unroll
            for (int r = 0; r < R; ++r) {
                cond[r] = sh_hdr[WS_COND + r];
#pragma unroll
                for (int f = 0; f < F; ++f) g[r][f] = sh_hdr[WS_G + r * F + f];
            }
            compute_m_exact(sf, W1, b1, W2, b2, W3, b3, m);
            compute_strength_exact(m, g, cond, st);
        }
    }

    sh_idx[tid] = (unsigned char)path_argmax(st);
    __syncthreads();

    float* outb = out + (size_t)blockIdx.x * (256 * A);
    for (int i = tid; i < 256 * A; i += 256) {
        int bl = i / A;
        int a  = i - bl * A;
        outb[i] = sh_hdr[WS_LEAVES + (int)sh_idx[bl] * A + a];
    }
}

// ---------------------------------------------------------------------------
// Cleanup: dense compacted list -> fully-active waves, one exact MLP per lane.
// ---------------------------------------------------------------------------
__global__ __launch_bounds__(256) void ftc_cleanup(
    const float* __restrict__ s,
    const float* __restrict__ W1, const float* __restrict__ b1,
    const float* __restrict__ W2, const float* __restrict__ b2,
    const float* __restrict__ W3, const float* __restrict__ b3,
    const float* __restrict__ ws,
    const unsigned int* __restrict__ list,
    float* __restrict__ out)
{
    const int count = ((const int*)ws)[WS_COUNT];
    for (int i = blockIdx.x * 256 + threadIdx.x; i < count; i += gridDim.x * 256) {
        const int e = (int)list[i];
        const float4 sv = *reinterpret_cast<const float4*>(s + (size_t)e * F);
        const float sf[F] = {sv.x, sv.y, sv.z, sv.w};
        float g[R][F], cond[R], m[R][F], st[R];
#pragma unroll
        for (int r = 0; r < R; ++r) {
            cond[r] = ws[WS_COND + r];
#pragma unroll
            for (int f = 0; f < F; ++f) g[r][f] = ws[WS_G + r * F + f];
        }
        compute_m_exact(sf, W1, b1, W2, b2, W3, b3, m);
        compute_strength_exact(m, g, cond, st);
        const int idx = path_argmax(st);
#pragma unroll
        for (int a = 0; a < A; ++a)
            out[(size_t)e * A + a] = ws[WS_LEAVES + idx * A + a];
    }
}

extern "C" void kernel_launch(void* const* d_in, const int* in_sizes, int n_in,
                              void* d_out, int out_size, void* d_ws, size_t ws_size,
                              hipStream_t stream) {
    const float* s  = (const float*)d_in[0];
    const float* W1 = (const float*)d_in[1];
    const float* b1 = (const float*)d_in[2];
    const float* W2 = (const float*)d_in[3];
    const float* b2 = (const float*)d_in[4];
    const float* W3 = (const float*)d_in[5];
    const float* b3 = (const float*)d_in[6];
    const float* ps = (const float*)d_in[7];
    const float* lv = (const float*)d_in[8];
    const float* gn = (const float*)d_in[9];
    float* ws  = (float*)d_ws;
    float* out = (float*)d_out;
    unsigned int* list = (unsigned int*)((char*)d_ws + WS_HDR_BYTES);
    const bool use_list = ws_size >= (size_t)WS_HDR_BYTES + sizeof(unsigned int) * (size_t)BTOT;

    hipLaunchKernelGGL(ftc_setup, dim3(1), dim3(256), 0, stream,
                       W1, b1, W2, b2, W3, b3, ps, gn, lv, ws);
    if (use_list) {
        hipLaunchKernelGGL((ftc_main<true>), dim3(BTOT / 256), dim3(256), 0, stream,
                           s, W1, b1, W2, b2, W3, b3, ws, list, out);
        hipLaunchKernelGGL(ftc_cleanup, dim3(128), dim3(256), 0, stream,
                           s, W1, b1, W2, b2, W3, b3, ws, list, out);
    } else {
        hipLaunchKernelGGL((ftc_main<false>), dim3(BTOT / 256), dim3(256), 0, stream,
                           s, W1, b1, W2, b2, W3, b3, ws, (unsigned int*)nullptr, out);
    }
}

// Round 6
// 41.958 us; speedup vs baseline: 3.2319x; 2.1327x over previous
//
#include <hip/hip_runtime.h>
#include <math.h>

#define BTOT 262144
#define R 3
#define F 4
#define H 16
#define A 18
#define SMALL_NUM_F 0.015f
#define MARGIN_TAU 1e-4f

// ---- ws header layout (float indices); index list follows at 768 B ----
#define WS_FLAG   0
#define WS_COUNT  1
#define WS_KP     4
#define WS_KM     20
#define WS_G      40
#define WS_COND   52
#define WS_LEAVES 56
#define WS_B3     128
#define WS_HDR_FLOATS 192
#define WS_HDR_BYTES  768

// ---------------------------------------------------------------------------
// Setup (1 block): batch-uniform quantities; K± f64-accumulated.
// ---------------------------------------------------------------------------
__global__ __launch_bounds__(256) void ftc_setup(
    const float* __restrict__ W1, const float* __restrict__ b1,
    const float* __restrict__ W2, const float* __restrict__ b2,
    const float* __restrict__ W3, const float* __restrict__ b3,
    const float* __restrict__ p_select, const float* __restrict__ gumbel,
    const float* __restrict__ leaves,
    float* __restrict__ ws)
{
    __shared__ int nz;
    __shared__ float sh_g[R * F];
    const int tid = threadIdx.x;
    if (tid == 0) nz = 0;
    __syncthreads();
    if (tid < R * F * H) {
        if (b1[tid] != 0.0f) atomicOr(&nz, 1);
        if (b2[tid] != 0.0f) atomicOr(&nz, 1);
    }

    if (tid < R * F) {   // g — verbatim round-1 float ops
        const int rf = tid;
        float l0 = p_select[rf * 2 + 0] + gumbel[rf * 2 + 0];
        float l1 = p_select[rf * 2 + 1] + gumbel[rf * 2 + 1];
        float mx = fmaxf(l0, l1);
        float e0 = expf(l0 - mx), e1 = expf(l1 - mx);
        float den = e0 + e1;
        float y0 = e0 / den, y1 = e1 / den;
        float ym = fmaxf(y0, y1);
        float g = (y1 == ym) ? 1.0f : 0.0f;
        sh_g[rf] = g;
        ws[WS_G + rf] = g;
        ws[WS_B3 + rf] = b3[rf];
    }
    if (tid < 4) {       // leaves softmax — verbatim round-1 float ops
        float mx = leaves[tid * A];
        for (int a = 1; a < A; ++a) mx = fmaxf(mx, leaves[tid * A + a]);
        float e[A];
        float sum = 0.f;
        for (int a = 0; a < A; ++a) { e[a] = expf(leaves[tid * A + a] - mx); sum += e[a]; }
        for (int a = 0; a < A; ++a) ws[WS_LEAVES + tid * A + a] = e[a] / sum;
    }
    if (tid < R * F) {   // K± collapse, f64
        const int rf = tid;
        double Kp = 0.0, Km = 0.0;
        for (int o = 0; o < H; ++o) {
            double Pp = 0.0, Pm = 0.0;
            for (int h = 0; h < H; ++h) {
                const double w1 = (double)W1[rf * H + h];
                const double w2 = (double)W2[rf * H * H + h * H + o];
                Pp += w1 * ((w1 > 0.0) ? 1.0 : 0.01) * w2;
                Pm += w1 * ((w1 < 0.0) ? 1.0 : 0.01) * w2;
            }
            const double w3 = (double)W3[rf * H + o];
            Kp += Pp * ((Pp > 0.0) ? 1.0 : 0.01) * w3;
            Km += Pm * ((Pm < 0.0) ? 1.0 : 0.01) * w3;
        }
        ws[WS_KP + rf] = (float)Kp;
        ws[WS_KM + rf] = (float)Km;
    }
    __syncthreads();
    if (tid == 0) {
        ((int*)ws)[WS_FLAG]  = (nz == 0) ? 1 : 0;
        ((int*)ws)[WS_COUNT] = 0;            // re-zeroed every launch (replay-safe)
    }
    if (tid < R) {
        float ssum = sh_g[tid * F + 0] + sh_g[tid * F + 1] + sh_g[tid * F + 2] + sh_g[tid * F + 3];
        ws[WS_COND + tid] = (ssum > SMALL_NUM_F) ? 1.0f : 0.0f;
    }
}

// ---------------------------------------------------------------------------
// Exact f32 chain — verbatim round-1 (measured absmax 0). Used by main's
// no-flag path only.
// ---------------------------------------------------------------------------
__device__ __forceinline__ void compute_m_exact(
    const float sf[F],
    const float* __restrict__ W1, const float* __restrict__ b1,
    const float* __restrict__ W2, const float* __restrict__ b2,
    const float* __restrict__ W3, const float* __restrict__ b3,
    float m[R][F])
{
#pragma unroll
    for (int r = 0; r < R; ++r) {
#pragma unroll
        for (int f = 0; f < F; ++f) {
            const int rf = r * F + f;
            const float* w1  = W1 + rf * H;
            const float* bb1 = b1 + rf * H;
            const float* w2  = W2 + rf * H * H;
            const float* bb2 = b2 + rf * H;
            const float* w3  = W3 + rf * H;
            float h1[H];
#pragma unroll
            for (int h = 0; h < H; ++h) {
                float v = fmaf(sf[f], w1[h], bb1[h]);
                h1[h] = fmaxf(v, 0.01f * v);
            }
            float acc[H];
#pragma unroll
            for (int o = 0; o < H; ++o) acc[o] = bb2[o];
#pragma unroll
            for (int h = 0; h < H; ++h) {
                const float hv = h1[h];
#pragma unroll
                for (int o = 0; o < H; ++o)
                    acc[o] = fmaf(hv, w2[h * H + o], acc[o]);
            }
            float dot = b3[rf];
#pragma unroll
            for (int o = 0; o < H; ++o) {
                float v = fmaxf(acc[o], 0.01f * acc[o]);
                dot = fmaf(v, w3[o], dot);
            }
            float mm = 1.0f / (1.0f + expf(-dot));
            m[r][f] = fmaxf(mm, SMALL_NUM_F);
        }
    }
}

__device__ __forceinline__ void compute_strength_exact(
    const float m[R][F], const float g[R][F], const float cond[R], float st[R])
{
#pragma unroll
    for (int r = 0; r < R; ++r) {
        const bool c = cond[r] != 0.0f;
        float X[F];
        float ssum = 0.f;
#pragma unroll
        for (int f = 0; f < F; ++f) {
            float gv = g[r][f];
            float xw = expf(0.1f * (gv / m[r][f]));
            if (c) xw *= gv;
            X[f] = xw;
            ssum += xw;
        }
        float sv = 0.f;
#pragma unroll
        for (int f = 0; f < F; ++f)
            sv += m[r][f] * (X[f] / ssum) * g[r][f];
        st[r] = isnan(sv) ? 0.0f : sv;
    }
}

__device__ __forceinline__ int path_argmax(const float st[R]) {
    const float r0 = st[0], r1 = st[1], r2 = st[2];
    const float p0 = r0 * r1;
    const float p1 = r0 * (1.0f - r1);
    const float p2 = (1.0f - r0) * r2;
    const float p3 = (1.0f - r0) * (1.0f - r2);
    int idx = 0;
    float best = p0;
    if (p1 > best) { best = p1; idx = 1; }
    if (p2 > best) { best = p2; idx = 2; }
    if (p3 > best) { best = p3; idx = 3; }
    return idx;
}

// ---------------------------------------------------------------------------
// Main: fast path; ambiguous elements appended to a compact index list.
// ---------------------------------------------------------------------------
template<bool USE_LIST>
__global__ __launch_bounds__(256) void ftc_main(
    const float* __restrict__ s,
    const float* __restrict__ W1, const float* __restrict__ b1,
    const float* __restrict__ W2, const float* __restrict__ b2,
    const float* __restrict__ W3, const float* __restrict__ b3,
    float* __restrict__ ws,
    unsigned int* __restrict__ list,
    float* __restrict__ out)
{
    __shared__ float sh_hdr[WS_HDR_FLOATS];
    __shared__ unsigned char sh_idx[256];

    const int tid = threadIdx.x;
    if (tid < WS_HDR_FLOATS) sh_hdr[tid] = ws[tid];
    __syncthreads();

    const int flag = (int)__float_as_uint(sh_hdr[WS_FLAG]);

    const int b = blockIdx.x * 256 + tid;
    const float4 sv = *reinterpret_cast<const float4*>(s + (size_t)b * F);
    const float sf[F] = {sv.x, sv.y, sv.z, sv.w};

    float st[R];
    bool need_exact = true;

    if (flag) {
#pragma unroll
        for (int r = 0; r < R; ++r) {
            const bool c = sh_hdr[WS_COND + r] != 0.0f;
            float num = 0.f, den = 0.f;
#pragma unroll
            for (int f = 0; f < F; ++f) {
                const int rf = r * F + f;
                const float k = (sf[f] > 0.0f) ? sh_hdr[WS_KP + rf] : sh_hdr[WS_KM + rf];
                const float dot = fmaf(sf[f], k, sh_hdr[WS_B3 + rf]);
                const float inv_m = fminf(1.0f + __expf(-dot), 1.0f / SMALL_NUM_F);
                const float mm = __builtin_amdgcn_rcpf(inv_m);
                const float g = sh_hdr[WS_G + rf];
                float xw = __expf(0.1f * g * inv_m);
                if (c) xw *= g;
                num = fmaf(mm * xw, g, num);
                den += xw;
            }
            st[r] = num * __builtin_amdgcn_rcpf(den);
        }
        const float r0 = st[0], r1 = st[1], r2 = st[2];
        const float p0 = r0 * r1;
        const float p1 = r0 * (1.0f - r1);
        const float p2 = (1.0f - r0) * r2;
        const float p3 = (1.0f - r0) * (1.0f - r2);
        const float a = fmaxf(p0, p1), bb = fminf(p0, p1);
        const float c2 = fmaxf(p2, p3), d = fminf(p2, p3);
        const float best = fmaxf(a, c2);
        const float second = fmaxf(fminf(a, c2), (a >= c2) ? bb : d);
        need_exact = !((best - second) > MARGIN_TAU);   // NaN-safe
    }

    if constexpr (USE_LIST) {
        if (flag) {
            if (need_exact) {
                unsigned int pos = atomicAdd((unsigned int*)ws + WS_COUNT, 1u);
                list[pos] = (unsigned int)b;
            }
        } else {
            float g[R][F], cond[R], m[R][F];
#pragma unroll
            for (int r = 0; r < R; ++r) {
                cond[r] = sh_hdr[WS_COND + r];
#pragma unroll
                for (int f = 0; f < F; ++f) g[r][f] = sh_hdr[WS_G + r * F + f];
            }
            compute_m_exact(sf, W1, b1, W2, b2, W3, b3, m);
            compute_strength_exact(m, g, cond, st);
        }
    } else {
        if (need_exact) {
            float g[R][F], cond[R], m[R][F];
#pragma unroll
            for (int r = 0; r < R; ++r) {
                cond[r] = sh_hdr[WS_COND + r];
#pragma unroll
                for (int f = 0; f < F; ++f) g[r][f] = sh_hdr[WS_G + r * F + f];
            }
            compute_m_exact(sf, W1, b1, W2, b2, W3, b3, m);
            compute_strength_exact(m, g, cond, st);
        }
    }

    sh_idx[tid] = (unsigned char)path_argmax(st);
    __syncthreads();

    float* outb = out + (size_t)blockIdx.x * (256 * A);
    for (int i = tid; i < 256 * A; i += 256) {
        int bl = i / A;
        int a  = i - bl * A;
        outb[i] = sh_hdr[WS_LEAVES + (int)sh_idx[bl] * A + a];
    }
}

// ---------------------------------------------------------------------------
// Cleanup v2: 16 lanes per flagged element; lane l<12 runs one (r,f) sub-MLP
// from LDS-staged weights (bit-exact op order vs compute_m_exact); m gathered
// via __shfl; strength/argmax recomputed redundantly on all lanes.
// LDS padding: stride 17 (W1/b1/b2/W3), stride 260 for W2 (16B-aligned float4
// reads, ≤2-way bank aliasing = free).
// ---------------------------------------------------------------------------
#define W2S 260
__global__ __launch_bounds__(256) void ftc_cleanup(
    const float* __restrict__ s,
    const float* __restrict__ W1, const float* __restrict__ b1,
    const float* __restrict__ W2, const float* __restrict__ b2,
    const float* __restrict__ W3, const float* __restrict__ b3,
    const float* __restrict__ ws,
    const unsigned int* __restrict__ list,
    float* __restrict__ out)
{
    const int count = ((const int*)ws)[WS_COUNT];
    if ((int)blockIdx.x * 16 >= count) return;   // uniform early-exit

    __shared__ float shW1[12 * 17], shB1[12 * 17], shB2[12 * 17], shW3[12 * 17];
    __shared__ float shW2[12 * W2S];
    __shared__ float shB3[12], shG[12], shCond[3], shLeaves[4 * A];

    const int tid = threadIdx.x;
    for (int i = tid; i < 192; i += 256) {
        const int rf = i >> 4, k = i & 15;
        shW1[rf * 17 + k] = W1[i];
        shB1[rf * 17 + k] = b1[i];
        shB2[rf * 17 + k] = b2[i];
        shW3[rf * 17 + k] = W3[i];
    }
    for (int i = tid; i < 3072; i += 256) {
        const int rf = i >> 8, k = i & 255;
        shW2[rf * W2S + k] = W2[i];
    }
    if (tid < 12) { shB3[tid] = ws[WS_B3 + tid]; shG[tid] = ws[WS_G + tid]; }
    if (tid < 3)  shCond[tid] = ws[WS_COND + tid];
    if (tid < 4 * A) shLeaves[tid] = ws[WS_LEAVES + tid];
    __syncthreads();

    const int l = tid & 15;                 // lane within group
    const int g0 = blockIdx.x * 16 + (tid >> 4);

    for (int i = g0; i < count; i += gridDim.x * 16) {
        const int e = (int)list[i];
        float mval = 0.f;
        if (l < 12) {
            const int rf = l;
            const int f = rf & 3;
            const float sfv = s[(size_t)e * F + f];
            float h1[H];
#pragma unroll
            for (int h = 0; h < H; ++h) {
                float v = fmaf(sfv, shW1[rf * 17 + h], shB1[rf * 17 + h]);
                h1[h] = fmaxf(v, 0.01f * v);
            }
            float acc[H];
#pragma unroll
            for (int o = 0; o < H; ++o) acc[o] = shB2[rf * 17 + o];
#pragma unroll
            for (int h = 0; h < H; ++h) {
                const float hv = h1[h];
#pragma unroll
                for (int c4 = 0; c4 < 4; ++c4) {
                    const float4 w2v = *reinterpret_cast<const float4*>(
                        &shW2[rf * W2S + h * 16 + c4 * 4]);
                    acc[c4 * 4 + 0] = fmaf(hv, w2v.x, acc[c4 * 4 + 0]);
                    acc[c4 * 4 + 1] = fmaf(hv, w2v.y, acc[c4 * 4 + 1]);
                    acc[c4 * 4 + 2] = fmaf(hv, w2v.z, acc[c4 * 4 + 2]);
                    acc[c4 * 4 + 3] = fmaf(hv, w2v.w, acc[c4 * 4 + 3]);
                }
            }
            float dot = shB3[rf];
#pragma unroll
            for (int o = 0; o < H; ++o) {
                float v = fmaxf(acc[o], 0.01f * acc[o]);
                dot = fmaf(v, shW3[rf * 17 + o], dot);
            }
            float mm = 1.0f / (1.0f + expf(-dot));
            mval = fmaxf(mm, SMALL_NUM_F);
        }
        // gather all 12 m values to every lane of the group
        float m[R][F], g[R][F], cond[R], st[R];
#pragma unroll
        for (int j = 0; j < 12; ++j) {
            const float mv = __shfl(mval, j, 16);
            m[j >> 2][j & 3] = mv;
        }
#pragma unroll
        for (int r = 0; r < R; ++r) {
            cond[r] = shCond[r];
#pragma unroll
            for (int f = 0; f < F; ++f) g[r][f] = shG[r * F + f];
        }
        compute_strength_exact(m, g, cond, st);
        const int idx = path_argmax(st);
        for (int a = l; a < A; a += 16)
            out[(size_t)e * A + a] = shLeaves[idx * A + a];
    }
}

extern "C" void kernel_launch(void* const* d_in, const int* in_sizes, int n_in,
                              void* d_out, int out_size, void* d_ws, size_t ws_size,
                              hipStream_t stream) {
    const float* s  = (const float*)d_in[0];
    const float* W1 = (const float*)d_in[1];
    const float* b1 = (const float*)d_in[2];
    const float* W2 = (const float*)d_in[3];
    const float* b2 = (const float*)d_in[4];
    const float* W3 = (const float*)d_in[5];
    const float* b3 = (const float*)d_in[6];
    const float* ps = (const float*)d_in[7];
    const float* lv = (const float*)d_in[8];
    const float* gn = (const float*)d_in[9];
    float* ws  = (float*)d_ws;
    float* out = (float*)d_out;
    unsigned int* list = (unsigned int*)((char*)d_ws + WS_HDR_BYTES);
    const bool use_list = ws_size >= (size_t)WS_HDR_BYTES + sizeof(unsigned int) * (size_t)BTOT;

    hipLaunchKernelGGL(ftc_setup, dim3(1), dim3(256), 0, stream,
                       W1, b1, W2, b2, W3, b3, ps, gn, lv, ws);
    if (use_list) {
        hipLaunchKernelGGL((ftc_main<true>), dim3(BTOT / 256), dim3(256), 0, stream,
                           s, W1, b1, W2, b2, W3, b3, ws, list, out);
        hipLaunchKernelGGL(ftc_cleanup, dim3(512), dim3(256), 0, stream,
                           s, W1, b1, W2, b2, W3, b3, ws, list, out);
    } else {
        hipLaunchKernelGGL((ftc_main<false>), dim3(BTOT / 256), dim3(256), 0, stream,
                           s, W1, b1, W2, b2, W3, b3, ws, (unsigned int*)nullptr, out);
    }
}